// Round 2
// baseline (1998.161 us; speedup 1.0000x reference)
//
#include <hip/hip_runtime.h>
#include <math.h>

#define HIDDEN 4096
#define NH 32
#define NKV 8
#define HD 128
#define BBATCH 2
#define SEQ 2048
#define BS 4096   // BBATCH*SEQ

typedef __attribute__((ext_vector_type(8))) short short8;
typedef __attribute__((ext_vector_type(4))) float f32x4;

__device__ __forceinline__ unsigned short f2bf(float f) {
  union { float f; unsigned int u; } v; v.f = f;
  unsigned int r = v.u + 0x7fffu + ((v.u >> 16) & 1u);
  return (unsigned short)(r >> 16);
}
__device__ __forceinline__ float bf2f(unsigned short u) {
  union { unsigned int u; float f; } v; v.u = ((unsigned int)u) << 16;
  return v.f;
}

// ---------------- fp32 -> bf16 cast (vectorized) ----------------
__global__ void cast_f32_bf16(const float* __restrict__ in, unsigned short* __restrict__ out) {
  int i = (blockIdx.x * blockDim.x + threadIdx.x) * 4;
  float4 f = *(const float4*)(in + i);
  ushort4 u;
  u.x = f2bf(f.x); u.y = f2bf(f.y); u.z = f2bf(f.z); u.w = f2bf(f.w);
  *(ushort4*)(out + i) = u;
}

// ---------------- GEMM: C[M,N] = A[M,K] * Bm[N,K]^T  (bf16 in, fp32 acc) ----------------
// 64x64 block tile, 4 waves, each wave 16 rows x 64 cols. LDS stride 40 (2-way conflict only, 16B aligned).
template<int OUT_F32>
__global__ __launch_bounds__(256) void gemm_bt(const unsigned short* __restrict__ A,
                                               const unsigned short* __restrict__ Bm,
                                               void* __restrict__ Cc,
                                               int M, int N, int K) {
  __shared__ unsigned short As[64 * 40];
  __shared__ unsigned short Bs[64 * 40];
  int t = threadIdx.x;
  int wave = t >> 6, lane = t & 63;
  int lm = lane & 15, quad = lane >> 4;
  int m0 = blockIdx.y * 64, n0 = blockIdx.x * 64;
  int srow = t >> 2, scol = (t & 3) * 8;
  f32x4 acc[4] = {};
  const unsigned short* ag = A + (size_t)(m0 + srow) * K + scol;
  const unsigned short* bg = Bm + (size_t)(n0 + srow) * K + scol;
  for (int k0 = 0; k0 < K; k0 += 32) {
    __syncthreads();
    *(uint4*)&As[srow * 40 + scol] = *(const uint4*)(ag + k0);
    *(uint4*)&Bs[srow * 40 + scol] = *(const uint4*)(bg + k0);
    __syncthreads();
    short8 af = *(const short8*)&As[(wave * 16 + lm) * 40 + quad * 8];
#pragma unroll
    for (int nt = 0; nt < 4; nt++) {
      short8 bfr = *(const short8*)&Bs[(nt * 16 + lm) * 40 + quad * 8];
      acc[nt] = __builtin_amdgcn_mfma_f32_16x16x32_bf16(af, bfr, acc[nt], 0, 0, 0);
    }
  }
#pragma unroll
  for (int nt = 0; nt < 4; nt++) {
#pragma unroll
    for (int r = 0; r < 4; r++) {
      size_t row = m0 + wave * 16 + quad * 4 + r;   // C/D: row = quad*4+reg (m89/m91 verified)
      size_t col = n0 + nt * 16 + lm;               //      col = lane&15
      if (OUT_F32) ((float*)Cc)[row * N + col] = acc[nt][r];
      else ((unsigned short*)Cc)[row * N + col] = f2bf(acc[nt][r]);
    }
  }
}

// ---------------- RoPE in-place on bf16 [rows, nheads, 128] ----------------
__global__ void rope_kernel(unsigned short* __restrict__ x, const int* __restrict__ pos_ids, int nheads) {
  int idx = blockIdx.x * blockDim.x + threadIdx.x;
  int j = idx & 63;
  int h = (idx >> 6) % nheads;
  int row = idx / (64 * nheads);
  int s = row & (SEQ - 1);
  float p = (float)pos_ids[s];
  // inv_freq = 10000^(-j/64) = 2^(-j*log2(10000)/64)
  float inv = exp2f(-(float)j * (13.287712379549449f / 64.0f));
  float f = p * inv;
  float c = cosf(f), sn = sinf(f);
  unsigned short* ptr = x + (size_t)row * (nheads * HD) + h * HD;
  float x1 = bf2f(ptr[j]), x2 = bf2f(ptr[j + 64]);
  ptr[j]      = f2bf(x1 * c - x2 * sn);
  ptr[j + 64] = f2bf(x2 * c + x1 * sn);
}

// ---------------- V transpose: [B,S,NKV,HD] -> [B,NKV,HD,S] ----------------
__global__ void transpose_v(const unsigned short* __restrict__ v, unsigned short* __restrict__ vt) {
  int idx = blockIdx.x * blockDim.x + threadIdx.x;
  int s = idx & (SEQ - 1);
  int d = (idx >> 11) & (HD - 1);
  int kv = (idx >> 18) & (NKV - 1);
  int b = idx >> 21;
  vt[idx] = v[(((size_t)(b * SEQ + s)) * NKV + kv) * HD + d];
}

// ---------------- Flash attention v2: per-wave 16 q-rows, 64-key tiles, no barriers ----------------
// Softmax in log2 domain (exp2 native), P round-trip through per-wave-private LDS (no __syncthreads).
__global__ __launch_bounds__(256) void attn_kernel(const unsigned short* __restrict__ Q,   // [B,S,NH*HD]
                                                   const unsigned short* __restrict__ Kb,  // [B,S,NKV*HD]
                                                   const unsigned short* __restrict__ Vt,  // [B,NKV,HD,S]
                                                   unsigned short* __restrict__ O) {       // [B,S,NH*HD]
  __shared__ unsigned short Plds[4][16 * 72];   // per-wave 16x64 P tile, stride 72 (16B aligned rows)
  int t = threadIdx.x, wave = t >> 6, lane = t & 63;
  int lm = lane & 15, quad = lane >> 4;
  int blk = blockIdx.x;
  int qt4 = blk & 31;          // 32 groups of 64 q rows
  int h = (blk >> 5) & 31;
  int b = blk >> 10;
  int kv = h >> 2;
  int qs0 = qt4 * 64 + wave * 16;
  // all softmax math in log2 domain: s_log2 = s * (1/sqrt(128)) * log2(e)
  const float c = 0.08838834764831845f * 1.4426950408889634f;

  // Q fragments (A-operand: m=lane&15, k=quad*8+j), 4 chunks of K=32 over d=128
  short8 aq[4];
  const unsigned short* qbase = Q + ((size_t)(b * SEQ + qs0 + lm)) * HIDDEN + h * HD;
#pragma unroll
  for (int kk = 0; kk < 4; kk++)
    aq[kk] = *(const short8*)(qbase + kk * 32 + quad * 8);

  f32x4 acc[8] = {};     // O accum, 8 d-subtiles of 16, C-layout
  float mrow[4] = {-1e30f, -1e30f, -1e30f, -1e30f};
  float lrow[4] = {0.f, 0.f, 0.f, 0.f};
  const unsigned short* kbase = Kb + ((size_t)b * SEQ) * (NKV * HD) + kv * HD;
  const unsigned short* vbase = Vt + ((size_t)(b * NKV + kv)) * HD * SEQ;
  unsigned short* pl = Plds[wave];

  for (int kblk = 0; kblk < SEQ; kblk += 64) {
    // S = Q K^T for 64 keys: four 16-col C tiles
    f32x4 sc[4] = {{}, {}, {}, {}};
#pragma unroll
    for (int kk = 0; kk < 4; kk++) {
#pragma unroll
      for (int kt = 0; kt < 4; kt++) {
        short8 bk = *(const short8*)(kbase + (size_t)(kblk + kt * 16 + lm) * (NKV * HD) + kk * 32 + quad * 8);
        sc[kt] = __builtin_amdgcn_mfma_f32_16x16x32_bf16(aq[kk], bk, sc[kt], 0, 0, 0);
      }
    }
    // online softmax (log2 domain). rows r = quad*4+r, cols across lm within quad-group.
    float alpha[4];
    float p[4][4];
#pragma unroll
    for (int r = 0; r < 4; r++) {
      float v = fmaxf(fmaxf(sc[0][r], sc[1][r]), fmaxf(sc[2][r], sc[3][r])) * c;
      v = fmaxf(v, __shfl_xor(v, 1));
      v = fmaxf(v, __shfl_xor(v, 2));
      v = fmaxf(v, __shfl_xor(v, 4));
      v = fmaxf(v, __shfl_xor(v, 8));
      float nm = fmaxf(mrow[r], v);
      alpha[r] = __builtin_amdgcn_exp2f(mrow[r] - nm);
      float rs = 0.f;
#pragma unroll
      for (int kt = 0; kt < 4; kt++) {
        p[kt][r] = __builtin_amdgcn_exp2f(sc[kt][r] * c - nm);
        rs += p[kt][r];
      }
      rs += __shfl_xor(rs, 1);
      rs += __shfl_xor(rs, 2);
      rs += __shfl_xor(rs, 4);
      rs += __shfl_xor(rs, 8);
      lrow[r] = lrow[r] * alpha[r] + rs;
      mrow[r] = nm;
    }
#pragma unroll
    for (int tt = 0; tt < 8; tt++) {
#pragma unroll
      for (int r = 0; r < 4; r++) acc[tt][r] *= alpha[r];
    }
    // P: C-layout -> per-wave LDS -> A-layout. No barrier needed (wave-private buffer).
#pragma unroll
    for (int r = 0; r < 4; r++) {
#pragma unroll
      for (int kt = 0; kt < 4; kt++)
        pl[(quad * 4 + r) * 72 + kt * 16 + lm] = f2bf(p[kt][r]);
    }
    short8 ap0 = *(const short8*)&pl[lm * 72 + quad * 8];
    short8 ap1 = *(const short8*)&pl[lm * 72 + 32 + quad * 8];
    // O += P * V  (B-operand from Vt: n=d=tt*16+lm, k=key, 16B contiguous)
#pragma unroll
    for (int tt = 0; tt < 8; tt++) {
      const unsigned short* vb = vbase + (size_t)(tt * 16 + lm) * SEQ + kblk + quad * 8;
      short8 bv0 = *(const short8*)(vb);
      short8 bv1 = *(const short8*)(vb + 32);
      acc[tt] = __builtin_amdgcn_mfma_f32_16x16x32_bf16(ap0, bv0, acc[tt], 0, 0, 0);
      acc[tt] = __builtin_amdgcn_mfma_f32_16x16x32_bf16(ap1, bv1, acc[tt], 0, 0, 0);
    }
  }
  // epilogue: normalize and store bf16 to [B,S,NH*HD]
#pragma unroll
  for (int r = 0; r < 4; r++) {
    float inv = 1.0f / lrow[r];
    int row = qs0 + quad * 4 + r;
    unsigned short* op = O + ((size_t)(b * SEQ + row)) * HIDDEN + h * HD;
#pragma unroll
    for (int tt = 0; tt < 8; tt++)
      op[tt * 16 + lm] = f2bf(acc[tt][r] * inv);
  }
}

extern "C" void kernel_launch(void* const* d_in, const int* in_sizes, int n_in,
                              void* d_out, int out_size, void* d_ws, size_t ws_size,
                              hipStream_t stream) {
  const float* hidden = (const float*)d_in[0];
  const int*   pos    = (const int*)d_in[1];
  const float* Wq     = (const float*)d_in[2];
  const float* Wk     = (const float*)d_in[3];
  const float* Wv     = (const float*)d_in[4];
  const float* Wo     = (const float*)d_in[5];

  char* ws = (char*)d_ws;
  unsigned short* hx = (unsigned short*)ws;  ws += (size_t)BS * HIDDEN * 2;        // 33.5MB
  unsigned short* wq = (unsigned short*)ws;  ws += (size_t)HIDDEN * HIDDEN * 2;    // 33.5MB
  unsigned short* wk = (unsigned short*)ws;  ws += (size_t)1024 * HIDDEN * 2;      // 8.4MB
  unsigned short* wv = (unsigned short*)ws;  ws += (size_t)1024 * HIDDEN * 2;      // 8.4MB
  unsigned short* wo = (unsigned short*)ws;  ws += (size_t)HIDDEN * HIDDEN * 2;    // 33.5MB
  unsigned short* qb = (unsigned short*)ws;  ws += (size_t)BS * HIDDEN * 2;        // 33.5MB
  unsigned short* kbf = (unsigned short*)ws; ws += (size_t)BS * 1024 * 2;          // 8.4MB
  unsigned short* vb = (unsigned short*)ws;  ws += (size_t)BS * 1024 * 2;          // 8.4MB
  unsigned short* vt = (unsigned short*)ws;  ws += (size_t)BS * 1024 * 2;          // 8.4MB
  unsigned short* ob = (unsigned short*)ws;  ws += (size_t)BS * HIDDEN * 2;        // 33.5MB

  // casts
  cast_f32_bf16<<<16384, 256, 0, stream>>>(hidden, hx);
  cast_f32_bf16<<<16384, 256, 0, stream>>>(Wq, wq);
  cast_f32_bf16<<<4096, 256, 0, stream>>>(Wk, wk);
  cast_f32_bf16<<<4096, 256, 0, stream>>>(Wv, wv);
  cast_f32_bf16<<<16384, 256, 0, stream>>>(Wo, wo);
  // projections
  gemm_bt<0><<<dim3(64, 64), 256, 0, stream>>>(hx, wq, qb, BS, HIDDEN, HIDDEN);
  gemm_bt<0><<<dim3(16, 64), 256, 0, stream>>>(hx, wk, kbf, BS, 1024, HIDDEN);
  gemm_bt<0><<<dim3(16, 64), 256, 0, stream>>>(hx, wv, vb, BS, 1024, HIDDEN);
  // rope
  rope_kernel<<<32768, 256, 0, stream>>>(qb, pos, NH);
  rope_kernel<<<8192, 256, 0, stream>>>(kbf, pos, NKV);
  // v transpose
  transpose_v<<<16384, 256, 0, stream>>>(vb, vt);
  // attention: blocks = B * NH * (S/64)
  attn_kernel<<<2048, 256, 0, stream>>>(qb, kbf, vt, ob);
  // output projection -> fp32 d_out
  gemm_bt<1><<<dim3(64, 64), 256, 0, stream>>>(ob, wo, d_out, BS, HIDDEN, HIDDEN);
}

// Round 3
// 1438.095 us; speedup vs baseline: 1.3894x; 1.3894x over previous
//
#include <hip/hip_runtime.h>
#include <math.h>

#define HIDDEN 4096
#define NH 32
#define NKV 8
#define HD 128
#define BBATCH 2
#define SEQ 2048
#define BS 4096   // BBATCH*SEQ
#define KVROW 1024  // NKV*HD

typedef __attribute__((ext_vector_type(8))) short short8;
typedef __attribute__((ext_vector_type(4))) float f32x4;

__device__ __forceinline__ unsigned short f2bf(float f) {
  union { float f; unsigned int u; } v; v.f = f;
  unsigned int r = v.u + 0x7fffu + ((v.u >> 16) & 1u);
  return (unsigned short)(r >> 16);
}
__device__ __forceinline__ float bf2f(unsigned short u) {
  union { unsigned int u; float f; } v; v.u = ((unsigned int)u) << 16;
  return v.f;
}

// ---------------- fp32 -> bf16 cast (vectorized) ----------------
__global__ void cast_f32_bf16(const float* __restrict__ in, unsigned short* __restrict__ out) {
  int i = (blockIdx.x * blockDim.x + threadIdx.x) * 4;
  float4 f = *(const float4*)(in + i);
  ushort4 u;
  u.x = f2bf(f.x); u.y = f2bf(f.y); u.z = f2bf(f.z); u.w = f2bf(f.w);
  *(ushort4*)(out + i) = u;
}

// ---------------- GEMM: C[M,N] = A[M,K] * Bm[N,K]^T  (bf16 in, fp32 acc) ----------------
template<int OUT_F32>
__global__ __launch_bounds__(256) void gemm_bt(const unsigned short* __restrict__ A,
                                               const unsigned short* __restrict__ Bm,
                                               void* __restrict__ Cc,
                                               int M, int N, int K) {
  __shared__ unsigned short As[64 * 40];
  __shared__ unsigned short Bs[64 * 40];
  int t = threadIdx.x;
  int wave = t >> 6, lane = t & 63;
  int lm = lane & 15, quad = lane >> 4;
  int m0 = blockIdx.y * 64, n0 = blockIdx.x * 64;
  int srow = t >> 2, scol = (t & 3) * 8;
  f32x4 acc[4] = {};
  const unsigned short* ag = A + (size_t)(m0 + srow) * K + scol;
  const unsigned short* bg = Bm + (size_t)(n0 + srow) * K + scol;
  for (int k0 = 0; k0 < K; k0 += 32) {
    __syncthreads();
    *(uint4*)&As[srow * 40 + scol] = *(const uint4*)(ag + k0);
    *(uint4*)&Bs[srow * 40 + scol] = *(const uint4*)(bg + k0);
    __syncthreads();
    short8 af = *(const short8*)&As[(wave * 16 + lm) * 40 + quad * 8];
#pragma unroll
    for (int nt = 0; nt < 4; nt++) {
      short8 bfr = *(const short8*)&Bs[(nt * 16 + lm) * 40 + quad * 8];
      acc[nt] = __builtin_amdgcn_mfma_f32_16x16x32_bf16(af, bfr, acc[nt], 0, 0, 0);
    }
  }
#pragma unroll
  for (int nt = 0; nt < 4; nt++) {
#pragma unroll
    for (int r = 0; r < 4; r++) {
      size_t row = m0 + wave * 16 + quad * 4 + r;
      size_t col = n0 + nt * 16 + lm;
      if (OUT_F32) ((float*)Cc)[row * N + col] = acc[nt][r];
      else ((unsigned short*)Cc)[row * N + col] = f2bf(acc[nt][r]);
    }
  }
}

// ---------------- RoPE in-place on bf16 [rows, nheads, 128] ----------------
__global__ void rope_kernel(unsigned short* __restrict__ x, const int* __restrict__ pos_ids, int nheads) {
  int idx = blockIdx.x * blockDim.x + threadIdx.x;
  int j = idx & 63;
  int h = (idx >> 6) % nheads;
  int row = idx / (64 * nheads);
  int s = row & (SEQ - 1);
  float p = (float)pos_ids[s];
  float inv = exp2f(-(float)j * (13.287712379549449f / 64.0f));
  float f = p * inv;
  float c = cosf(f), sn = sinf(f);
  unsigned short* ptr = x + (size_t)row * (nheads * HD) + h * HD;
  float x1 = bf2f(ptr[j]), x2 = bf2f(ptr[j + 64]);
  ptr[j]      = f2bf(x1 * c - x2 * sn);
  ptr[j + 64] = f2bf(x2 * c + x1 * sn);
}

// ---------------- V transpose: [B,S,NKV,HD] -> [B,NKV,HD,S] ----------------
__global__ void transpose_v(const unsigned short* __restrict__ v, unsigned short* __restrict__ vt) {
  int idx = blockIdx.x * blockDim.x + threadIdx.x;
  int s = idx & (SEQ - 1);
  int d = (idx >> 11) & (HD - 1);
  int kv = (idx >> 18) & (NKV - 1);
  int b = idx >> 21;
  vt[idx] = v[(((size_t)(b * SEQ + s)) * NKV + kv) * HD + d];
}

// ---------------- Flash attention v3: LDS-staged K/V tiles, 128 q-rows/block ----------------
// Block: 4 waves x 32 q-rows (2 A-frag sets each). Per 64-key iter: cooperatively stage
// K(64x128) and V(128x64) tiles coalesced into LDS, shared by all waves. Strides chosen so
// all ds_read_b128 are bank-uniform (68/36 dwords == 4 mod 32 -> 8 accesses/bank).
__global__ __launch_bounds__(256, 3) void attn_kernel(const unsigned short* __restrict__ Q,   // [B,S,NH*HD]
                                                      const unsigned short* __restrict__ Kb,  // [B,S,NKV*HD]
                                                      const unsigned short* __restrict__ Vt,  // [B,NKV,HD,S]
                                                      unsigned short* __restrict__ O) {       // [B,S,NH*HD]
  __shared__ unsigned short Ks[64 * 136];   // [key][d], stride 136 shorts
  __shared__ unsigned short Vs[128 * 72];   // [d][key], stride 72 shorts
  __shared__ unsigned short Plds[4][16 * 72];
  int t = threadIdx.x, wave = t >> 6, lane = t & 63;
  int lm = lane & 15, quad = lane >> 4;
  int blk = blockIdx.x;
  int qt = blk & 15;           // 16 tiles of 128 q rows
  int h = (blk >> 4) & 31;
  int b = blk >> 9;
  int kv = h >> 2;
  int qs0 = qt * 128 + wave * 32;
  const float c = 0.08838834764831845f * 1.4426950408889634f;  // scale * log2(e)

  // Q fragments: 2 sets of 16 rows, 4 K-chunks of 32 over d=128
  short8 aq[2][4];
#pragma unroll
  for (int s = 0; s < 2; s++) {
    const unsigned short* qbase = Q + ((size_t)(b * SEQ + qs0 + s * 16 + lm)) * HIDDEN + h * HD;
#pragma unroll
    for (int kk = 0; kk < 4; kk++)
      aq[s][kk] = *(const short8*)(qbase + kk * 32 + quad * 8);
  }

  f32x4 acc[2][8] = {};
  float mrow[2][4] = {{-1e30f,-1e30f,-1e30f,-1e30f},{-1e30f,-1e30f,-1e30f,-1e30f}};
  float lrow[2][4] = {};
  const unsigned short* kbase = Kb + (size_t)b * SEQ * KVROW + kv * HD;
  const unsigned short* vbase = Vt + ((size_t)(b * NKV + kv)) * HD * SEQ;
  unsigned short* pl = Plds[wave];

  int krow = t >> 4, kcol = (t & 15) * 8;   // K staging: 16 key-rows/pass, 128 d each
  int vrow = t >> 3, vcol = (t & 7) * 8;    // V staging: 32 d-rows/pass, 64 keys each

  for (int kblk = 0; kblk < SEQ; kblk += 64) {
    // ---- cooperative coalesced staging ----
#pragma unroll
    for (int pp = 0; pp < 4; pp++) {
      *(uint4*)&Ks[(pp * 16 + krow) * 136 + kcol] =
          *(const uint4*)(kbase + (size_t)(kblk + pp * 16 + krow) * KVROW + kcol);
      *(uint4*)&Vs[(pp * 32 + vrow) * 72 + vcol] =
          *(const uint4*)(vbase + (size_t)(pp * 32 + vrow) * SEQ + kblk + vcol);
    }
    __syncthreads();
    // ---- S = Q K^T: 4 key-subtiles x 4 d-chunks, K ds_reads shared across both q-sets ----
    f32x4 sc[2][4] = {{{},{},{},{}},{{},{},{},{}}};
#pragma unroll
    for (int kt = 0; kt < 4; kt++) {
#pragma unroll
      for (int kk = 0; kk < 4; kk++) {
        short8 bk = *(const short8*)&Ks[(kt * 16 + lm) * 136 + kk * 32 + quad * 8];
        sc[0][kt] = __builtin_amdgcn_mfma_f32_16x16x32_bf16(aq[0][kk], bk, sc[0][kt], 0, 0, 0);
        sc[1][kt] = __builtin_amdgcn_mfma_f32_16x16x32_bf16(aq[1][kk], bk, sc[1][kt], 0, 0, 0);
      }
    }
    // ---- online softmax (log2 domain) + P -> LDS -> A-frag, per set ----
    short8 ap[2][2];
#pragma unroll
    for (int s = 0; s < 2; s++) {
      float alpha[4];
      float p[4][4];
#pragma unroll
      for (int r = 0; r < 4; r++) {
        float v = fmaxf(fmaxf(sc[s][0][r], sc[s][1][r]), fmaxf(sc[s][2][r], sc[s][3][r])) * c;
        v = fmaxf(v, __shfl_xor(v, 1));
        v = fmaxf(v, __shfl_xor(v, 2));
        v = fmaxf(v, __shfl_xor(v, 4));
        v = fmaxf(v, __shfl_xor(v, 8));
        float nm = fmaxf(mrow[s][r], v);
        alpha[r] = __builtin_amdgcn_exp2f(mrow[s][r] - nm);
        float rs = 0.f;
#pragma unroll
        for (int kt = 0; kt < 4; kt++) {
          p[kt][r] = __builtin_amdgcn_exp2f(sc[s][kt][r] * c - nm);
          rs += p[kt][r];
        }
        rs += __shfl_xor(rs, 1);
        rs += __shfl_xor(rs, 2);
        rs += __shfl_xor(rs, 4);
        rs += __shfl_xor(rs, 8);
        lrow[s][r] = lrow[s][r] * alpha[r] + rs;
        mrow[s][r] = nm;
      }
#pragma unroll
      for (int tt = 0; tt < 8; tt++) {
#pragma unroll
        for (int r = 0; r < 4; r++) acc[s][tt][r] *= alpha[r];
      }
#pragma unroll
      for (int r = 0; r < 4; r++) {
#pragma unroll
        for (int kt = 0; kt < 4; kt++)
          pl[(quad * 4 + r) * 72 + kt * 16 + lm] = f2bf(p[kt][r]);
      }
      ap[s][0] = *(const short8*)&pl[lm * 72 + quad * 8];
      ap[s][1] = *(const short8*)&pl[lm * 72 + 32 + quad * 8];
    }
    // ---- O += P V: V ds_reads shared across both q-sets ----
#pragma unroll
    for (int tt = 0; tt < 8; tt++) {
      const unsigned short* vp = &Vs[(tt * 16 + lm) * 72 + quad * 8];
      short8 bv0 = *(const short8*)(vp);
      short8 bv1 = *(const short8*)(vp + 32);
      acc[0][tt] = __builtin_amdgcn_mfma_f32_16x16x32_bf16(ap[0][0], bv0, acc[0][tt], 0, 0, 0);
      acc[0][tt] = __builtin_amdgcn_mfma_f32_16x16x32_bf16(ap[0][1], bv1, acc[0][tt], 0, 0, 0);
      acc[1][tt] = __builtin_amdgcn_mfma_f32_16x16x32_bf16(ap[1][0], bv0, acc[1][tt], 0, 0, 0);
      acc[1][tt] = __builtin_amdgcn_mfma_f32_16x16x32_bf16(ap[1][1], bv1, acc[1][tt], 0, 0, 0);
    }
    __syncthreads();
  }
  // epilogue
#pragma unroll
  for (int s = 0; s < 2; s++) {
#pragma unroll
    for (int r = 0; r < 4; r++) {
      float inv = 1.0f / lrow[s][r];
      int row = qs0 + s * 16 + quad * 4 + r;
      unsigned short* op = O + ((size_t)(b * SEQ + row)) * HIDDEN + h * HD;
#pragma unroll
      for (int tt = 0; tt < 8; tt++)
        op[tt * 16 + lm] = f2bf(acc[s][tt][r] * inv);
    }
  }
}

extern "C" void kernel_launch(void* const* d_in, const int* in_sizes, int n_in,
                              void* d_out, int out_size, void* d_ws, size_t ws_size,
                              hipStream_t stream) {
  const float* hidden = (const float*)d_in[0];
  const int*   pos    = (const int*)d_in[1];
  const float* Wq     = (const float*)d_in[2];
  const float* Wk     = (const float*)d_in[3];
  const float* Wv     = (const float*)d_in[4];
  const float* Wo     = (const float*)d_in[5];

  char* ws = (char*)d_ws;
  unsigned short* hx = (unsigned short*)ws;  ws += (size_t)BS * HIDDEN * 2;
  unsigned short* wq = (unsigned short*)ws;  ws += (size_t)HIDDEN * HIDDEN * 2;
  unsigned short* wk = (unsigned short*)ws;  ws += (size_t)1024 * HIDDEN * 2;
  unsigned short* wv = (unsigned short*)ws;  ws += (size_t)1024 * HIDDEN * 2;
  unsigned short* wo = (unsigned short*)ws;  ws += (size_t)HIDDEN * HIDDEN * 2;
  unsigned short* qb = (unsigned short*)ws;  ws += (size_t)BS * HIDDEN * 2;
  unsigned short* kbf = (unsigned short*)ws; ws += (size_t)BS * 1024 * 2;
  unsigned short* vb = (unsigned short*)ws;  ws += (size_t)BS * 1024 * 2;
  unsigned short* vt = (unsigned short*)ws;  ws += (size_t)BS * 1024 * 2;
  unsigned short* ob = (unsigned short*)ws;  ws += (size_t)BS * HIDDEN * 2;

  cast_f32_bf16<<<16384, 256, 0, stream>>>(hidden, hx);
  cast_f32_bf16<<<16384, 256, 0, stream>>>(Wq, wq);
  cast_f32_bf16<<<4096, 256, 0, stream>>>(Wk, wk);
  cast_f32_bf16<<<4096, 256, 0, stream>>>(Wv, wv);
  cast_f32_bf16<<<16384, 256, 0, stream>>>(Wo, wo);
  gemm_bt<0><<<dim3(64, 64), 256, 0, stream>>>(hx, wq, qb, BS, HIDDEN, HIDDEN);
  gemm_bt<0><<<dim3(16, 64), 256, 0, stream>>>(hx, wk, kbf, BS, 1024, HIDDEN);
  gemm_bt<0><<<dim3(16, 64), 256, 0, stream>>>(hx, wv, vb, BS, 1024, HIDDEN);
  rope_kernel<<<32768, 256, 0, stream>>>(qb, pos, NH);
  rope_kernel<<<8192, 256, 0, stream>>>(kbf, pos, NKV);
  transpose_v<<<16384, 256, 0, stream>>>(vb, vt);
  // attention: blocks = B * NH * (S/128) = 2*32*16
  attn_kernel<<<1024, 256, 0, stream>>>(qb, kbf, vt, ob);
  gemm_bt<1><<<dim3(64, 64), 256, 0, stream>>>(ob, wo, d_out, BS, HIDDEN, HIDDEN);
}

// Round 4
// 1178.182 us; speedup vs baseline: 1.6960x; 1.2206x over previous
//
#include <hip/hip_runtime.h>
#include <math.h>

#define HIDDEN 4096
#define NH 32
#define NKV 8
#define HD 128
#define BBATCH 2
#define SEQ 2048
#define BS 4096     // BBATCH*SEQ
#define KVROW 1024  // NKV*HD

typedef __attribute__((ext_vector_type(8))) short short8;
typedef __attribute__((ext_vector_type(4))) short short4v;
typedef __attribute__((ext_vector_type(4))) float f32x4;

#if defined(__has_builtin)
#if __has_builtin(__builtin_amdgcn_mfma_f32_16x16x16bf16_1k)
#define HAVE_MFMA16 1
#endif
#endif

__device__ __forceinline__ unsigned short f2bf(float f) {
  union { float f; unsigned int u; } v; v.f = f;
  unsigned int r = v.u + 0x7fffu + ((v.u >> 16) & 1u);
  return (unsigned short)(r >> 16);
}
__device__ __forceinline__ float bf2f(unsigned short u) {
  union { unsigned int u; float f; } v; v.u = ((unsigned int)u) << 16;
  return v.f;
}

// async global->LDS, 16B per lane. LDS dest must be uniform base + lane*16.
__device__ __forceinline__ void gload16(const unsigned short* g, unsigned short* l) {
  __builtin_amdgcn_global_load_lds((const __attribute__((address_space(1))) unsigned int*)(const void*)g,
                                   (__attribute__((address_space(3))) unsigned int*)(void*)l, 16, 0, 0);
}

// ---------------- fp32 -> bf16 cast ----------------
__global__ void cast_f32_bf16(const float* __restrict__ in, unsigned short* __restrict__ out) {
  int i = (blockIdx.x * blockDim.x + threadIdx.x) * 4;
  float4 f = *(const float4*)(in + i);
  ushort4 u;
  u.x = f2bf(f.x); u.y = f2bf(f.y); u.z = f2bf(f.z); u.w = f2bf(f.w);
  *(ushort4*)(out + i) = u;
}

// ---------------- GEMM m97-style: C[M,N] = A[M,K]*Bm[N,K]^T, 128x128 tile ----------------
// global_load_lds width16, unpadded 128x32 LDS tiles, XOR swizzle (colgrp ^= row&3) applied on
// the global-read side so the lane-ordered LDS write stays contiguous; frag reads land 2-way max.
template<int OUT_F32>
__global__ __launch_bounds__(256) void gemm_bt128(const unsigned short* __restrict__ A,
                                                  const unsigned short* __restrict__ Bm,
                                                  void* __restrict__ Cc,
                                                  int M, int N, int K) {
  __shared__ unsigned short As[128 * 32];
  __shared__ unsigned short Bs[128 * 32];
  int t = threadIdx.x, lane = t & 63, wave = t >> 6;
  int lm = lane & 15, quad = lane >> 4;
  int wm = wave >> 1, wn = wave & 1;
  int m0 = blockIdx.y * 128, n0 = blockIdx.x * 128;
  int srow = t >> 2;                               // 0..63
  int pcol = (((t & 3) ^ (srow & 3)) * 8);         // swizzled column group (shorts)
  f32x4 acc[4][4] = {};
  const unsigned short* ag = A + (size_t)(m0 + srow) * K + pcol;
  const unsigned short* bg = Bm + (size_t)(n0 + srow) * K + pcol;
  unsigned short* asl = &As[(size_t)t * 8];
  unsigned short* bsl = &Bs[(size_t)t * 8];
  for (int k0 = 0; k0 < K; k0 += 32) {
    __syncthreads();
    gload16(ag + k0, asl);
    gload16(ag + (size_t)64 * K + k0, asl + 2048);
    gload16(bg + k0, bsl);
    gload16(bg + (size_t)64 * K + k0, bsl + 2048);
    __syncthreads();
    int xq = (quad ^ (lm & 3)) * 8;
    short8 af[4], bf[4];
#pragma unroll
    for (int mt = 0; mt < 4; mt++)
      af[mt] = *(const short8*)&As[(wm * 64 + mt * 16 + lm) * 32 + xq];
#pragma unroll
    for (int nt = 0; nt < 4; nt++)
      bf[nt] = *(const short8*)&Bs[(wn * 64 + nt * 16 + lm) * 32 + xq];
#pragma unroll
    for (int mt = 0; mt < 4; mt++)
#pragma unroll
      for (int nt = 0; nt < 4; nt++)
        acc[mt][nt] = __builtin_amdgcn_mfma_f32_16x16x32_bf16(af[mt], bf[nt], acc[mt][nt], 0, 0, 0);
  }
#pragma unroll
  for (int mt = 0; mt < 4; mt++)
#pragma unroll
    for (int nt = 0; nt < 4; nt++)
#pragma unroll
      for (int r = 0; r < 4; r++) {
        size_t row = m0 + wm * 64 + mt * 16 + quad * 4 + r;
        size_t col = n0 + wn * 64 + nt * 16 + lm;
        if (OUT_F32) ((float*)Cc)[row * N + col] = acc[mt][nt][r];
        else ((unsigned short*)Cc)[row * N + col] = f2bf(acc[mt][nt][r]);
      }
}

// ---------------- RoPE in-place on bf16 [rows, nheads, 128] ----------------
__global__ void rope_kernel(unsigned short* __restrict__ x, const int* __restrict__ pos_ids, int nheads) {
  int idx = blockIdx.x * blockDim.x + threadIdx.x;
  int j = idx & 63;
  int h = (idx >> 6) % nheads;
  int row = idx / (64 * nheads);
  int s = row & (SEQ - 1);
  float p = (float)pos_ids[s];
  float inv = exp2f(-(float)j * (13.287712379549449f / 64.0f));
  float f = p * inv;
  float c = cosf(f), sn = sinf(f);
  unsigned short* ptr = x + (size_t)row * (nheads * HD) + h * HD;
  float x1 = bf2f(ptr[j]), x2 = bf2f(ptr[j + 64]);
  ptr[j]      = f2bf(x1 * c - x2 * sn);
  ptr[j + 64] = f2bf(x2 * c + x1 * sn);
}

// ---------------- V transpose: [B,S,NKV,HD] -> [B,NKV,HD,S] ----------------
__global__ void transpose_v(const unsigned short* __restrict__ v, unsigned short* __restrict__ vt) {
  int idx = blockIdx.x * blockDim.x + threadIdx.x;
  int s = idx & (SEQ - 1);
  int d = (idx >> 11) & (HD - 1);
  int kv = (idx >> 18) & (NKV - 1);
  int b = idx >> 21;
  vt[idx] = v[(((size_t)(b * SEQ + s)) * NKV + kv) * HD + d];
}

// ---------------- Flash attention v4: operand-swapped S^T = K Q^T ----------------
// Score C-layout (m=key=quad*4+r, n=q=lm) IS the K=16 MFMA A-layout (m=lm, k=quad*4+j):
// P feeds PV directly from registers (no LDS round-trip). Softmax: in-lane over 16 regs
// + xor16/xor32 shuffles. alpha/l broadcast to acc rows via __shfl(quad*4+r).
__global__ __launch_bounds__(256) void attn_kernel(const unsigned short* __restrict__ Q,   // [B,S,NH*HD]
                                                   const unsigned short* __restrict__ Kb,  // [B,S,NKV*HD]
                                                   const unsigned short* __restrict__ Vt,  // [B,NKV,HD,S]
                                                   unsigned short* __restrict__ O) {       // [B,S,NH*HD]
  __shared__ unsigned short Ks[64 * 136];   // [key][d], stride 136 shorts
  __shared__ unsigned short Vs[128 * 72];   // [d][key], stride 72 shorts
#ifndef HAVE_MFMA16
  __shared__ unsigned short Plds[4][16 * 72];
#endif
  int t = threadIdx.x, wave = t >> 6, lane = t & 63;
  int lm = lane & 15, quad = lane >> 4;
  int blk = blockIdx.x;
  int qt = blk & 15;
  int h = (blk >> 4) & 31;
  int b = blk >> 9;
  int kv = h >> 2;
  int qs0 = qt * 128 + wave * 32;
  const float c = 0.08838834764831845f * 1.4426950408889634f;  // 1/sqrt(128) * log2(e)

  // Q fragments (used as B-operand: n=q=lm, k=d=quad*8+j)
  short8 aq[2][4];
#pragma unroll
  for (int s = 0; s < 2; s++) {
    const unsigned short* qbase = Q + ((size_t)(b * SEQ + qs0 + s * 16 + lm)) * HIDDEN + h * HD;
#pragma unroll
    for (int kk = 0; kk < 4; kk++)
      aq[s][kk] = *(const short8*)(qbase + kk * 32 + quad * 8);
  }

  f32x4 acc[2][8] = {};     // O: row=q=quad*4+r, col=d=lm (per tt d-subtile)
  float mrow[2] = {-1e30f, -1e30f};
  float lrow[2] = {0.f, 0.f};
  const unsigned short* kbase = Kb + (size_t)b * SEQ * KVROW + kv * HD;
  const unsigned short* vbase = Vt + ((size_t)(b * NKV + kv)) * HD * SEQ;

  int krow = t >> 4, kcol = (t & 15) * 8;
  int vrow = t >> 3, vcol = (t & 7) * 8;

  for (int kblk = 0; kblk < SEQ; kblk += 64) {
    // ---- cooperative coalesced staging ----
#pragma unroll
    for (int pp = 0; pp < 4; pp++) {
      *(uint4*)&Ks[(pp * 16 + krow) * 136 + kcol] =
          *(const uint4*)(kbase + (size_t)(kblk + pp * 16 + krow) * KVROW + kcol);
      *(uint4*)&Vs[(pp * 32 + vrow) * 72 + vcol] =
          *(const uint4*)(vbase + (size_t)(pp * 32 + vrow) * SEQ + kblk + vcol);
    }
    __syncthreads();
    // ---- S^T = K Q^T : A = K-frag (m=key, k=d), B = Q-frag (n=q, k=d) ----
    f32x4 sc[2][4] = {{{},{},{},{}},{{},{},{},{}}};
#pragma unroll
    for (int kt = 0; kt < 4; kt++) {
#pragma unroll
      for (int kk = 0; kk < 4; kk++) {
        short8 bk = *(const short8*)&Ks[(kt * 16 + lm) * 136 + kk * 32 + quad * 8];
        sc[0][kt] = __builtin_amdgcn_mfma_f32_16x16x32_bf16(bk, aq[0][kk], sc[0][kt], 0, 0, 0);
        sc[1][kt] = __builtin_amdgcn_mfma_f32_16x16x32_bf16(bk, aq[1][kk], sc[1][kt], 0, 0, 0);
      }
    }
    // ---- online softmax (log2 domain); lane owns q-row = lm, keys kt*16+quad*4+r ----
    short4v pfrag[2][4];
#pragma unroll
    for (int s = 0; s < 2; s++) {
      float vmax = -1e30f;
#pragma unroll
      for (int kt = 0; kt < 4; kt++)
#pragma unroll
        for (int r = 0; r < 4; r++) vmax = fmaxf(vmax, sc[s][kt][r]);
      vmax *= c;
      vmax = fmaxf(vmax, __shfl_xor(vmax, 16));
      vmax = fmaxf(vmax, __shfl_xor(vmax, 32));
      float nm = fmaxf(mrow[s], vmax);
      float alpha = __builtin_amdgcn_exp2f(mrow[s] - nm);
      mrow[s] = nm;
      float rs = 0.f;
#pragma unroll
      for (int kt = 0; kt < 4; kt++) {
#pragma unroll
        for (int r = 0; r < 4; r++) {
          float pv = __builtin_amdgcn_exp2f(sc[s][kt][r] * c - nm);
          rs += pv;
          pfrag[s][kt][r] = (short)f2bf(pv);
        }
      }
      rs += __shfl_xor(rs, 16);
      rs += __shfl_xor(rs, 32);
      lrow[s] = lrow[s] * alpha + rs;
#pragma unroll
      for (int r = 0; r < 4; r++) {
        float ar = __shfl(alpha, quad * 4 + r);
#pragma unroll
        for (int tt = 0; tt < 8; tt++) acc[s][tt][r] *= ar;
      }
    }
#ifdef HAVE_MFMA16
    // ---- O += P V via K=16 MFMA, P direct from registers ----
#pragma unroll
    for (int tt = 0; tt < 8; tt++) {
#pragma unroll
      for (int kt = 0; kt < 4; kt++) {
        short4v bv = *(const short4v*)&Vs[(tt * 16 + lm) * 72 + kt * 16 + quad * 4];
        acc[0][tt] = __builtin_amdgcn_mfma_f32_16x16x16bf16_1k(pfrag[0][kt], bv, acc[0][tt], 0, 0, 0);
        acc[1][tt] = __builtin_amdgcn_mfma_f32_16x16x16bf16_1k(pfrag[1][kt], bv, acc[1][tt], 0, 0, 0);
      }
    }
#else
    // ---- fallback: vectorized b64 P round-trip, then K=32 PV ----
    short8 ap[2][2];
    unsigned short* pl = Plds[wave];
#pragma unroll
    for (int s = 0; s < 2; s++) {
#pragma unroll
      for (int kt = 0; kt < 4; kt++)
        *(short4v*)&pl[lm * 72 + kt * 16 + quad * 4] = pfrag[s][kt];
      ap[s][0] = *(const short8*)&pl[lm * 72 + quad * 8];
      ap[s][1] = *(const short8*)&pl[lm * 72 + 32 + quad * 8];
    }
#pragma unroll
    for (int tt = 0; tt < 8; tt++) {
      const unsigned short* vp = &Vs[(tt * 16 + lm) * 72 + quad * 8];
      short8 bv0 = *(const short8*)(vp);
      short8 bv1 = *(const short8*)(vp + 32);
      acc[0][tt] = __builtin_amdgcn_mfma_f32_16x16x32_bf16(ap[0][0], bv0, acc[0][tt], 0, 0, 0);
      acc[0][tt] = __builtin_amdgcn_mfma_f32_16x16x32_bf16(ap[0][1], bv1, acc[0][tt], 0, 0, 0);
      acc[1][tt] = __builtin_amdgcn_mfma_f32_16x16x32_bf16(ap[1][0], bv0, acc[1][tt], 0, 0, 0);
      acc[1][tt] = __builtin_amdgcn_mfma_f32_16x16x32_bf16(ap[1][1], bv1, acc[1][tt], 0, 0, 0);
    }
#endif
    __syncthreads();
  }
  // epilogue: acc row q=quad*4+r needs l from lane lm=quad*4+r
#pragma unroll
  for (int s = 0; s < 2; s++) {
#pragma unroll
    for (int r = 0; r < 4; r++) {
      float lq = __shfl(lrow[s], quad * 4 + r);
      float inv = 1.0f / lq;
      int row = qs0 + s * 16 + quad * 4 + r;
      unsigned short* op = O + ((size_t)(b * SEQ + row)) * HIDDEN + h * HD;
#pragma unroll
      for (int tt = 0; tt < 8; tt++)
        op[tt * 16 + lm] = f2bf(acc[s][tt][r] * inv);
    }
  }
}

extern "C" void kernel_launch(void* const* d_in, const int* in_sizes, int n_in,
                              void* d_out, int out_size, void* d_ws, size_t ws_size,
                              hipStream_t stream) {
  const float* hidden = (const float*)d_in[0];
  const int*   pos    = (const int*)d_in[1];
  const float* Wq     = (const float*)d_in[2];
  const float* Wk     = (const float*)d_in[3];
  const float* Wv     = (const float*)d_in[4];
  const float* Wo     = (const float*)d_in[5];

  char* ws = (char*)d_ws;
  unsigned short* hx = (unsigned short*)ws;  ws += (size_t)BS * HIDDEN * 2;
  unsigned short* wq = (unsigned short*)ws;  ws += (size_t)HIDDEN * HIDDEN * 2;
  unsigned short* wk = (unsigned short*)ws;  ws += (size_t)1024 * HIDDEN * 2;
  unsigned short* wv = (unsigned short*)ws;  ws += (size_t)1024 * HIDDEN * 2;
  unsigned short* wo = (unsigned short*)ws;  ws += (size_t)HIDDEN * HIDDEN * 2;
  unsigned short* qb = (unsigned short*)ws;  ws += (size_t)BS * HIDDEN * 2;
  unsigned short* kbf = (unsigned short*)ws; ws += (size_t)BS * 1024 * 2;
  unsigned short* vb = (unsigned short*)ws;  ws += (size_t)BS * 1024 * 2;
  unsigned short* vt = (unsigned short*)ws;  ws += (size_t)BS * 1024 * 2;
  unsigned short* ob = (unsigned short*)ws;  ws += (size_t)BS * HIDDEN * 2;

  cast_f32_bf16<<<16384, 256, 0, stream>>>(hidden, hx);
  cast_f32_bf16<<<16384, 256, 0, stream>>>(Wq, wq);
  cast_f32_bf16<<<4096, 256, 0, stream>>>(Wk, wk);
  cast_f32_bf16<<<4096, 256, 0, stream>>>(Wv, wv);
  cast_f32_bf16<<<16384, 256, 0, stream>>>(Wo, wo);
  gemm_bt128<0><<<dim3(32, 32), 256, 0, stream>>>(hx, wq, qb, BS, HIDDEN, HIDDEN);
  gemm_bt128<0><<<dim3(8, 32), 256, 0, stream>>>(hx, wk, kbf, BS, 1024, HIDDEN);
  gemm_bt128<0><<<dim3(8, 32), 256, 0, stream>>>(hx, wv, vb, BS, 1024, HIDDEN);
  rope_kernel<<<32768, 256, 0, stream>>>(qb, pos, NH);
  rope_kernel<<<8192, 256, 0, stream>>>(kbf, pos, NKV);
  transpose_v<<<16384, 256, 0, stream>>>(vb, vt);
  attn_kernel<<<1024, 256, 0, stream>>>(qb, kbf, vt, ob);
  gemm_bt128<1><<<dim3(32, 32), 256, 0, stream>>>(ob, wo, d_out, BS, HIDDEN, HIDDEN);
}